// Round 13
// baseline (74.700 us; speedup 1.0000x reference)
//
#include <hip/hip_runtime.h>

#define T_STEPS 32768
#define NROWS 188
#define NWAVES 12      // row-blocks of 16 rows (188 -> 12 blocks, last padded)
#define CHAINS 3       // independent recurrence chains per wave (ILP)
#define NSUPER 4       // NWAVES / CHAINS
#define SEGS 256       // parallel-in-time segments
#define SEG_LEN (T_STEPS / SEGS)   // 128
#define WARMUP 32      // washout; HW-certified r8-r12 (absmax at algebra floor)
#define UB 8           // unroll/batch width (divides WARMUP and SEG_LEN)

typedef float f2 __attribute__((ext_vector_type(2)));

__device__ __forceinline__ float fexp2(float x) { return __builtin_amdgcn_exp2f(x); }
__device__ __forceinline__ float frcp(float x) { return __builtin_amdgcn_rcpf(x); }
#define SBAR() __builtin_amdgcn_sched_barrier(0)

// Guaranteed-packed FMA: d = a*b + c elementwise on both f32 halves.
// ALL VOP3P-f32 operands must be 64-bit VGPR pairs (r5 lesson).
__device__ __forceinline__ f2 pk_fma(f2 a, f2 b, f2 c) {
  f2 d;
  asm("v_pk_fma_f32 %0, %1, %2, %3"
      : "=v"(d)
      : "v"(a), "v"(b), "v"(c));
  return d;
}

__device__ __forceinline__ f2 mkpair(float a) {
  f2 r = {a, a};
  return r;
}

// Broadcast lane (quad_base + J)'s value to all 4 lanes of the quad (DPP quad_perm).
template <int J>
__device__ __forceinline__ float qbcast(float v) {
  int i = __builtin_amdgcn_mov_dpp(__builtin_bit_cast(int, v), J * 0x55, 0xF, 0xF, true);
  return __builtin_bit_cast(float, i);
}

// ONE wave per workgroup (r9: multi-wave WGs imbalance per-SIMD wave counts).
// Each wave runs CHAINS=3 independent chains (row-blocks b = blockIdx.x*3+c) at
// time segment s = blockIdx.y.
// r11/r12 lesson: source-level phase structure is NOT binding — the machine
// scheduler sank each chain's ops back together (VGPR=64 both rounds), fully
// serializing the chains. Fix (rule #18/T19): __builtin_amdgcn_sched_barrier(0)
// at the two phase boundaries — the scheduler cannot cross it, so all 3
// chains' pa/pb (and num/rD/oC) are forced live across the barrier and the
// transcendental latency of each chain hides under the other two chains' issue.
//   phase 1: 3x {10 pk_fma pre-activation trees}        -> pa[c], pb[c]
//   SBAR
//   phase 2: 3x {4 exp2, denominators, rcp}             -> num[c], rD[c], oC[c]
//   SBAR
//   phase 3: 3x {c-update, exp2, rcp, h, o}
// Step math unchanged since r7 (7 transcendentals/step).
// Segment s emits t in [s*SEG_LEN,(s+1)*SEG_LEN) after washout from
// t0 = max(0, s*SEG_LEN - WARMUP) at zero state (segment 0: true h0/c0).
template <bool USE_WS>
__global__ __launch_bounds__(64) void lstm_scan_kernel(
    const float* __restrict__ x, const float* __restrict__ h0v,
    const float* __restrict__ c0v, const float* __restrict__ Wf,
    const float* __restrict__ bf, const float* __restrict__ Wi,
    const float* __restrict__ bi, const float* __restrict__ Wc,
    const float* __restrict__ bc, const float* __restrict__ Wo,
    const float* __restrict__ bo, const float* __restrict__ Ww,
    float* __restrict__ dst) {
  const int l = threadIdx.x;
  const int r = l >> 2;
  const int g = l & 3;

  const float S1 = -1.4426950408889634f;
  const float S2 = -2.8853900817779268f;

  // shared packed weights: .x = {f|c} member, .y = {i|o} member
  const f2 wa0 = {S1 * Wf[g * 5 + 0], S1 * Wi[g * 5 + 0]};
  const f2 wa1 = {S1 * Wf[g * 5 + 1], S1 * Wi[g * 5 + 1]};
  const f2 wa2 = {S1 * Wf[g * 5 + 2], S1 * Wi[g * 5 + 2]};
  const f2 wa3 = {S1 * Wf[g * 5 + 3], S1 * Wi[g * 5 + 3]};
  const f2 wa4 = {S1 * Wf[g * 5 + 4], S1 * Wi[g * 5 + 4]};
  const f2 ba  = {S1 * bf[g],          S1 * bi[g]};
  const f2 wb0 = {S2 * Wc[g * 5 + 0], S1 * Wo[g * 5 + 0]};
  const f2 wb1 = {S2 * Wc[g * 5 + 1], S1 * Wo[g * 5 + 1]};
  const f2 wb2 = {S2 * Wc[g * 5 + 2], S1 * Wo[g * 5 + 2]};
  const f2 wb3 = {S2 * Wc[g * 5 + 3], S1 * Wo[g * 5 + 3]};
  const f2 wb4 = {S2 * Wc[g * 5 + 4], S1 * Wo[g * 5 + 4]};
  const f2 bb  = {S2 * bc[g],          S1 * bo[g]};

  int nidx[CHAINS];
  float wwn[CHAINS];
#pragma unroll
  for (int c = 0; c < CHAINS; ++c) {
    int n = (blockIdx.x * CHAINS + c) * 16 + r;
    const bool valid = (n < NROWS);
    if (!valid) n = NROWS - 1;  // dummy lanes duplicate row 187, contribute 0
    nidx[c] = n;
    wwn[c] = valid ? Ww[n] : 0.0f;
  }

  const int s = blockIdx.y;
  const int seg_start = s * SEG_LEN;
  int t0 = seg_start - WARMUP;
  if (t0 < 0) t0 = 0;

  float h[CHAINS], cp[CHAINS];
#pragma unroll
  for (int c = 0; c < CHAINS; ++c) {
    if (s == 0) {
      h[c] = h0v[nidx[c] * 4 + g];
      cp[c] = S2 * c0v[nidx[c] * 4 + g];
    } else {
      h[c] = 0.0f;
      cp[c] = 0.0f;
    }
  }

  // phase-split tri-step with sched_barrier-pinned phase boundaries
  auto tri_step = [&](const float xv[CHAINS], float oo[CHAINS]) {
    f2 pa[CHAINS], pb[CHAINS];
    // ---- phase 1: pre-activation FMA trees (all chains) ----
#pragma unroll
    for (int c = 0; c < CHAINS; ++c) {
      const f2 xp = mkpair(xv[c]);
      f2 a_ = pk_fma(xp, wa0, ba);
      f2 b_ = pk_fma(xp, wb0, bb);
      const f2 h0p = mkpair(qbcast<0>(h[c]));
      const f2 h1p = mkpair(qbcast<1>(h[c]));
      const f2 h2p = mkpair(qbcast<2>(h[c]));
      const f2 h3p = mkpair(qbcast<3>(h[c]));
      a_ = pk_fma(h0p, wa1, a_);  b_ = pk_fma(h0p, wb1, b_);
      a_ = pk_fma(h1p, wa2, a_);  b_ = pk_fma(h1p, wb2, b_);
      a_ = pk_fma(h2p, wa3, a_);  b_ = pk_fma(h2p, wb3, b_);
      a_ = pk_fma(h3p, wa4, a_);  b_ = pk_fma(h3p, wb4, b_);
      pa[c] = a_;  pb[c] = b_;
    }
    SBAR();  // scheduler may not sink phase-1 ops past this point
    // ---- phase 2: gate transcendentals -> num, rD, oC (all chains) ----
    float num[CHAINS], rD[CHAINS], oCv[CHAINS];
#pragma unroll
    for (int c = 0; c < CHAINS; ++c) {
      const float A  = fexp2(pa[c].x);
      const float B  = fexp2(pa[c].y);
      const float Ec = fexp2(pb[c].x);
      const float C  = fexp2(pb[c].y);
      const float oA  = 1.0f + A;
      const float oB  = 1.0f + B;
      const float oEc = 1.0f + Ec;
      oCv[c] = 1.0f + C;
      const float t1 = oB * oEc;
      const float t2 = fmaf(-S2, Ec, S2) * oA;   // S2*(1-Ec)*(1+A)
      num[c] = fmaf(cp[c], t1, t2);
      rD[c] = frcp(t1 * oA);
    }
    SBAR();
    // ---- phase 3: state update + output transcendentals (all chains) ----
#pragma unroll
    for (int c = 0; c < CHAINS; ++c) {
      cp[c] = fminf(num[c] * rD[c], 60.0f);      // S2*cn; clamp keeps 2^cp finite
      const float E = fexp2(cp[c]);
      const float oE = 1.0f + E;
      const float rT = frcp(oE * oCv[c]);
      h[c] = (1.0f - E) * rT;                    // tanh(cn) * o
      oo[c] = oE * rT;                           // o
    }
  };

  float xa[CHAINS][UB], xb[CHAINS][UB];
#pragma unroll
  for (int u = 0; u < UB; ++u)
#pragma unroll
    for (int c = 0; c < CHAINS; ++c) xa[c][u] = x[(t0 + u) * NROWS + nidx[c]];

  // ---- warmup (washout): no output; prefetch stays < seg_start+UB <= T ----
  for (int t = t0; t < seg_start; t += UB) {
#pragma unroll
    for (int u = 0; u < UB; ++u)
#pragma unroll
      for (int c = 0; c < CHAINS; ++c) xb[c][u] = x[(t + UB + u) * NROWS + nidx[c]];
#pragma unroll
    for (int u = 0; u < UB; ++u) {
      float xv[CHAINS], oo[CHAINS];
#pragma unroll
      for (int c = 0; c < CHAINS; ++c) xv[c] = xa[c][u];
      tri_step(xv, oo);
    }
#pragma unroll
    for (int u = 0; u < UB; ++u)
#pragma unroll
      for (int c = 0; c < CHAINS; ++c) xa[c][u] = xb[c][u];
  }

  // ---- main segment: batch UB tri-steps, then batched cross-lane reduce ----
  for (int t = seg_start; t < seg_start + SEG_LEN; t += UB) {
#pragma unroll
    for (int u = 0; u < UB; ++u) {
      int tp = t + UB + u;                    // uniform -> scalar cmp/select
      if (tp > T_STEPS - 1) tp = T_STEPS - 1;
#pragma unroll
      for (int c = 0; c < CHAINS; ++c) xb[c][u] = x[tp * NROWS + nidx[c]];
    }
    float ov[CHAINS][UB];
#pragma unroll
    for (int u = 0; u < UB; ++u) {
      float xv[CHAINS], oo[CHAINS];
#pragma unroll
      for (int c = 0; c < CHAINS; ++c) xv[c] = xa[c][u];
      tri_step(xv, oo);
#pragma unroll
      for (int c = 0; c < CHAINS; ++c) ov[c][u] = oo[c] * wwn[c];
    }
#pragma unroll
    for (int u = 0; u < UB; ++u)
#pragma unroll
      for (int c = 0; c < CHAINS; ++c) ov[c][u] += __shfl_xor(ov[c][u], 4);
#pragma unroll
    for (int u = 0; u < UB; ++u)
#pragma unroll
      for (int c = 0; c < CHAINS; ++c) ov[c][u] += __shfl_xor(ov[c][u], 8);
#pragma unroll
    for (int u = 0; u < UB; ++u)
#pragma unroll
      for (int c = 0; c < CHAINS; ++c) ov[c][u] += __shfl_xor(ov[c][u], 16);
#pragma unroll
    for (int u = 0; u < UB; ++u)
#pragma unroll
      for (int c = 0; c < CHAINS; ++c) ov[c][u] += __shfl_xor(ov[c][u], 32);
    if (l < 4) {
#pragma unroll
      for (int c = 0; c < CHAINS; ++c) {
        const int b = blockIdx.x * CHAINS + c;
        if constexpr (USE_WS) {
          float* pt = dst + (size_t)b * T_STEPS * 4;
#pragma unroll
          for (int u = 0; u < UB; ++u) pt[(t + u) * 4 + l] = ov[c][u];
        } else {
#pragma unroll
          for (int u = 0; u < UB; ++u) atomicAdd(&dst[(t + u) * 4 + l], ov[c][u]);
        }
      }
    }
#pragma unroll
    for (int u = 0; u < UB; ++u)
#pragma unroll
      for (int c = 0; c < CHAINS; ++c) xa[c][u] = xb[c][u];
  }
}

__global__ __launch_bounds__(256) void reduce_out_kernel(
    const float* __restrict__ partial, const float* __restrict__ bwp,
    float* __restrict__ out) {
  const int idx = blockIdx.x * 256 + threadIdx.x;
  if (idx >= T_STEPS * 4) return;
  float s = bwp[0];
#pragma unroll
  for (int w = 0; w < NWAVES; ++w) s += partial[(size_t)w * T_STEPS * 4 + idx];
  out[idx] = s;
}

__global__ __launch_bounds__(256) void init_out_kernel(
    const float* __restrict__ bwp, float* __restrict__ out) {
  const int idx = blockIdx.x * 256 + threadIdx.x;
  if (idx < T_STEPS * 4) out[idx] = bwp[0];
}

extern "C" void kernel_launch(void* const* d_in, const int* in_sizes, int n_in,
                              void* d_out, int out_size, void* d_ws, size_t ws_size,
                              hipStream_t stream) {
  const float* x  = (const float*)d_in[0];
  const float* h0 = (const float*)d_in[1];
  const float* c0 = (const float*)d_in[2];
  const float* Wf = (const float*)d_in[3];
  const float* bf = (const float*)d_in[4];
  const float* Wi = (const float*)d_in[5];
  const float* bi = (const float*)d_in[6];
  const float* Wc = (const float*)d_in[7];
  const float* bc = (const float*)d_in[8];
  const float* Wo = (const float*)d_in[9];
  const float* bo = (const float*)d_in[10];
  const float* Ww = (const float*)d_in[11];
  const float* bw = (const float*)d_in[12];
  float* out = (float*)d_out;

  const size_t need = (size_t)NWAVES * T_STEPS * 4 * sizeof(float);
  const int nout_blocks = (T_STEPS * 4 + 255) / 256;
  const dim3 grid(NSUPER, SEGS);
  if (ws_size >= need) {
    float* partial = (float*)d_ws;
    lstm_scan_kernel<true><<<grid, 64, 0, stream>>>(
        x, h0, c0, Wf, bf, Wi, bi, Wc, bc, Wo, bo, Ww, partial);
    reduce_out_kernel<<<nout_blocks, 256, 0, stream>>>(partial, bw, out);
  } else {
    init_out_kernel<<<nout_blocks, 256, 0, stream>>>(bw, out);
    lstm_scan_kernel<false><<<grid, 64, 0, stream>>>(
        x, h0, c0, Wf, bf, Wi, bi, Wc, bc, Wo, bo, Ww, out);
  }
}

// Round 14
// 63.257 us; speedup vs baseline: 1.1809x; 1.1809x over previous
//
#include <hip/hip_runtime.h>

#define T_STEPS 32768
#define NROWS 188
#define NBLOCKS 6      // row-blocks of 32 rows (6*32=192 >= 188, last 4 padded)
#define SEGS 512       // parallel-in-time segments; 6*512=3072 waves = 3/SIMD balanced
#define SEG_LEN (T_STEPS / SEGS)   // 64
#define WARMUP 32      // washout; HW-certified r8-r13 (absmax at algebra floor)
#define UB 8           // unroll/batch width (divides WARMUP and SEG_LEN)

typedef float f2 __attribute__((ext_vector_type(2)));

__device__ __forceinline__ float fexp2(float x) { return __builtin_amdgcn_exp2f(x); }
__device__ __forceinline__ float frcp(float x) { return __builtin_amdgcn_rcpf(x); }

// Guaranteed-packed FMA: d = a*b + c elementwise on both f32 halves.
// ALL VOP3P-f32 operands must be 64-bit VGPR pairs (r5 lesson).
__device__ __forceinline__ f2 pk_fma(f2 a, f2 b, f2 c) {
  f2 d;
  asm("v_pk_fma_f32 %0, %1, %2, %3" : "=v"(d) : "v"(a), "v"(b), "v"(c));
  return d;
}

__device__ __forceinline__ f2 mkpair(float a) {
  f2 r = {a, a};
  return r;
}

// ===== 2-lanes-per-row layout (r14) =====
// r10-r13 lesson: with 4 lanes/row the wave spends 13.75 issue-cy per row-step
// and chain-ILP attempts are undone by the compiler. Here lane l = 2*r + p
// owns cells (2p, 2p+1) of row n = blockIdx.x*32 + r: 32 rows per wave.
// Per step: partner h-pair via 2 shfl_xor(.,1); all-gate pre-activations as
// 20 pk_fma on f2(cell-pair) with per-lane PRE-SWIZZLED weights (z-order
// [x, own.x, own.y, oth.x, oth.y] -> weight cols picked at init by parity);
// then the r7 per-cell algebra verbatim (5 exp2 + 2 rcp per cell).
// Output: o-pair * Ww[n]; butterfly over same-parity lanes (masks 2..32);
// lane 0 holds cells(0,1) sum, lane 1 cells(2,3) -> one b64 store each.
// Segment s = blockIdx.y emits t in [s*L, (s+1)*L) after washout from
// t0 = max(0, s*L - WARMUP) at zero state (segment 0: true h0/c0).
template <bool USE_WS>
__global__ __launch_bounds__(64) void lstm_scan_kernel(
    const float* __restrict__ x, const float* __restrict__ h0v,
    const float* __restrict__ c0v, const float* __restrict__ Wf,
    const float* __restrict__ bf, const float* __restrict__ Wi,
    const float* __restrict__ bi, const float* __restrict__ Wc,
    const float* __restrict__ bc, const float* __restrict__ Wo,
    const float* __restrict__ bo, const float* __restrict__ Ww,
    float* __restrict__ dst) {
  const int l = threadIdx.x;
  const int r = l >> 1;
  const int p = l & 1;
  int n = blockIdx.x * 32 + r;
  const bool valid = (n < NROWS);
  if (!valid) n = NROWS - 1;  // dummy rows duplicate row 187, contribute 0

  const float S1 = -1.4426950408889634f;
  const float S2 = -2.8853900817779268f;

  const int c0 = 2 * p, c1 = 2 * p + 1;      // own cells
  const int d0 = 2 - 2 * p, d1 = 3 - 2 * p;  // partner lane's cells

  // per-lane packed weights over the cell pair (c0,c1); z-order swizzled:
  // pre = b + x*wx + own.x*wn0 + own.y*wn1 + oth.x*wt0 + oth.y*wt1
#define LOADW(W, S)                                                     \
  {                                                                     \
    {S * W[c0 * 5 + 0], S * W[c1 * 5 + 0]},        /* wx  */            \
    {S * W[c0 * 5 + 1 + c0], S * W[c1 * 5 + 1 + c0]}, /* wn0 */         \
    {S * W[c0 * 5 + 1 + c1], S * W[c1 * 5 + 1 + c1]}, /* wn1 */         \
    {S * W[c0 * 5 + 1 + d0], S * W[c1 * 5 + 1 + d0]}, /* wt0 */         \
    {S * W[c0 * 5 + 1 + d1], S * W[c1 * 5 + 1 + d1]}  /* wt1 */         \
  }
  const f2 wF[5] = LOADW(Wf, S1);
  const f2 wI[5] = LOADW(Wi, S1);
  const f2 wC[5] = LOADW(Wc, S2);
  const f2 wO[5] = LOADW(Wo, S1);
#undef LOADW
  const f2 bF = {S1 * bf[c0], S1 * bf[c1]};
  const f2 bI = {S1 * bi[c0], S1 * bi[c1]};
  const f2 bC = {S2 * bc[c0], S2 * bc[c1]};
  const f2 bO = {S1 * bo[c0], S1 * bo[c1]};
  const float wwn = valid ? Ww[n] : 0.0f;

  const int s = blockIdx.y;
  const int seg_start = s * SEG_LEN;
  int t0 = seg_start - WARMUP;
  if (t0 < 0) t0 = 0;

  f2 hm;            // own cells' h
  float cpA, cpB;   // S2-scaled c for cells c0, c1
  if (s == 0) {
    const f2 hv = *(const f2*)&h0v[n * 4 + 2 * p];
    const f2 cv = *(const f2*)&c0v[n * 4 + 2 * p];
    hm = hv;
    cpA = S2 * cv.x;
    cpB = S2 * cv.y;
  } else {
    hm = (f2){0.0f, 0.0f};
    cpA = 0.0f;
    cpB = 0.0f;
  }

  float* pt = nullptr;
  if constexpr (USE_WS) pt = dst + (size_t)blockIdx.x * T_STEPS * 4;

  // one step; returns the lane's 2 o-gate values
  auto step = [&](float xv, float& oA_, float& oB_) {
    const float ox = __shfl_xor(hm.x, 1);
    const float oy = __shfl_xor(hm.y, 1);
    const f2 xp  = mkpair(xv);
    const f2 a0  = mkpair(hm.x);
    const f2 a1  = mkpair(hm.y);
    const f2 b0  = mkpair(ox);
    const f2 b1  = mkpair(oy);
    f2 pF = pk_fma(xp, wF[0], bF);
    f2 pI = pk_fma(xp, wI[0], bI);
    f2 pC = pk_fma(xp, wC[0], bC);
    f2 pO = pk_fma(xp, wO[0], bO);
    pF = pk_fma(a0, wF[1], pF); pI = pk_fma(a0, wI[1], pI);
    pC = pk_fma(a0, wC[1], pC); pO = pk_fma(a0, wO[1], pO);
    pF = pk_fma(a1, wF[2], pF); pI = pk_fma(a1, wI[2], pI);
    pC = pk_fma(a1, wC[2], pC); pO = pk_fma(a1, wO[2], pO);
    pF = pk_fma(b0, wF[3], pF); pI = pk_fma(b0, wI[3], pI);
    pC = pk_fma(b0, wC[3], pC); pO = pk_fma(b0, wO[3], pO);
    pF = pk_fma(b1, wF[4], pF); pI = pk_fma(b1, wI[4], pI);
    pC = pk_fma(b1, wC[4], pC); pO = pk_fma(b1, wO[4], pO);
    // ---- cell c0 (components .x), r7 algebra verbatim ----
    {
      const float A  = fexp2(pF.x);
      const float B  = fexp2(pI.x);
      const float Ec = fexp2(pC.x);
      const float C  = fexp2(pO.x);
      const float oA  = 1.0f + A;
      const float oB  = 1.0f + B;
      const float oEc = 1.0f + Ec;
      const float oC  = 1.0f + C;
      const float t1 = oB * oEc;
      const float t2 = fmaf(-S2, Ec, S2) * oA;
      const float num = fmaf(cpA, t1, t2);
      const float rD = frcp(t1 * oA);
      cpA = fminf(num * rD, 60.0f);
      const float E = fexp2(cpA);
      const float oE = 1.0f + E;
      const float rT = frcp(oE * oC);
      hm.x = (1.0f - E) * rT;
      oA_ = oE * rT;
    }
    // ---- cell c1 (components .y) ----
    {
      const float A  = fexp2(pF.y);
      const float B  = fexp2(pI.y);
      const float Ec = fexp2(pC.y);
      const float C  = fexp2(pO.y);
      const float oA  = 1.0f + A;
      const float oB  = 1.0f + B;
      const float oEc = 1.0f + Ec;
      const float oC  = 1.0f + C;
      const float t1 = oB * oEc;
      const float t2 = fmaf(-S2, Ec, S2) * oA;
      const float num = fmaf(cpB, t1, t2);
      const float rD = frcp(t1 * oA);
      cpB = fminf(num * rD, 60.0f);
      const float E = fexp2(cpB);
      const float oE = 1.0f + E;
      const float rT = frcp(oE * oC);
      hm.y = (1.0f - E) * rT;
      oB_ = oE * rT;
    }
  };

  float xa[UB], xb[UB];
#pragma unroll
  for (int u = 0; u < UB; ++u) xa[u] = x[(t0 + u) * NROWS + n];

  // ---- warmup (washout): no output; prefetch stays < seg_start+UB <= T ----
  for (int t = t0; t < seg_start; t += UB) {
#pragma unroll
    for (int u = 0; u < UB; ++u) xb[u] = x[(t + UB + u) * NROWS + n];
#pragma unroll
    for (int u = 0; u < UB; ++u) {
      float oA_, oB_;
      step(xa[u], oA_, oB_);
    }
#pragma unroll
    for (int u = 0; u < UB; ++u) xa[u] = xb[u];
  }

  // ---- main segment: batch UB steps, then batched same-parity reduce ----
  for (int t = seg_start; t < seg_start + SEG_LEN; t += UB) {
#pragma unroll
    for (int u = 0; u < UB; ++u) {
      int tp = t + UB + u;                    // uniform -> scalar cmp/select
      if (tp > T_STEPS - 1) tp = T_STEPS - 1;
      xb[u] = x[tp * NROWS + n];
    }
    float ovA[UB], ovB[UB];
#pragma unroll
    for (int u = 0; u < UB; ++u) {
      float oA_, oB_;
      step(xa[u], oA_, oB_);
      ovA[u] = oA_ * wwn;
      ovB[u] = oB_ * wwn;
    }
    // butterfly over same-parity lanes (32 rows): masks 2,4,8,16,32
#pragma unroll
    for (int u = 0; u < UB; ++u) { ovA[u] += __shfl_xor(ovA[u], 2);  ovB[u] += __shfl_xor(ovB[u], 2); }
#pragma unroll
    for (int u = 0; u < UB; ++u) { ovA[u] += __shfl_xor(ovA[u], 4);  ovB[u] += __shfl_xor(ovB[u], 4); }
#pragma unroll
    for (int u = 0; u < UB; ++u) { ovA[u] += __shfl_xor(ovA[u], 8);  ovB[u] += __shfl_xor(ovB[u], 8); }
#pragma unroll
    for (int u = 0; u < UB; ++u) { ovA[u] += __shfl_xor(ovA[u], 16); ovB[u] += __shfl_xor(ovB[u], 16); }
#pragma unroll
    for (int u = 0; u < UB; ++u) { ovA[u] += __shfl_xor(ovA[u], 32); ovB[u] += __shfl_xor(ovB[u], 32); }
    // lane 0 holds cells (0,1) sums; lane 1 holds cells (2,3) sums
    if (l < 2) {
      if constexpr (USE_WS) {
#pragma unroll
        for (int u = 0; u < UB; ++u) {
          f2 v = {ovA[u], ovB[u]};
          *(f2*)&pt[(t + u) * 4 + 2 * l] = v;
        }
      } else {
#pragma unroll
        for (int u = 0; u < UB; ++u) {
          atomicAdd(&dst[(t + u) * 4 + 2 * l + 0], ovA[u]);
          atomicAdd(&dst[(t + u) * 4 + 2 * l + 1], ovB[u]);
        }
      }
    }
#pragma unroll
    for (int u = 0; u < UB; ++u) xa[u] = xb[u];
  }
}

__global__ __launch_bounds__(256) void reduce_out_kernel(
    const float* __restrict__ partial, const float* __restrict__ bwp,
    float* __restrict__ out) {
  const int idx = blockIdx.x * 256 + threadIdx.x;
  if (idx >= T_STEPS * 4) return;
  float s = bwp[0];
#pragma unroll
  for (int w = 0; w < NBLOCKS; ++w) s += partial[(size_t)w * T_STEPS * 4 + idx];
  out[idx] = s;
}

__global__ __launch_bounds__(256) void init_out_kernel(
    const float* __restrict__ bwp, float* __restrict__ out) {
  const int idx = blockIdx.x * 256 + threadIdx.x;
  if (idx < T_STEPS * 4) out[idx] = bwp[0];
}

extern "C" void kernel_launch(void* const* d_in, const int* in_sizes, int n_in,
                              void* d_out, int out_size, void* d_ws, size_t ws_size,
                              hipStream_t stream) {
  const float* x  = (const float*)d_in[0];
  const float* h0 = (const float*)d_in[1];
  const float* c0 = (const float*)d_in[2];
  const float* Wf = (const float*)d_in[3];
  const float* bf = (const float*)d_in[4];
  const float* Wi = (const float*)d_in[5];
  const float* bi = (const float*)d_in[6];
  const float* Wc = (const float*)d_in[7];
  const float* bc = (const float*)d_in[8];
  const float* Wo = (const float*)d_in[9];
  const float* bo = (const float*)d_in[10];
  const float* Ww = (const float*)d_in[11];
  const float* bw = (const float*)d_in[12];
  float* out = (float*)d_out;

  const size_t need = (size_t)NBLOCKS * T_STEPS * 4 * sizeof(float);
  const int nout_blocks = (T_STEPS * 4 + 255) / 256;
  const dim3 grid(NBLOCKS, SEGS);
  if (ws_size >= need) {
    float* partial = (float*)d_ws;
    lstm_scan_kernel<true><<<grid, 64, 0, stream>>>(
        x, h0, c0, Wf, bf, Wi, bi, Wc, bc, Wo, bo, Ww, partial);
    reduce_out_kernel<<<nout_blocks, 256, 0, stream>>>(partial, bw, out);
  } else {
    init_out_kernel<<<nout_blocks, 256, 0, stream>>>(bw, out);
    lstm_scan_kernel<false><<<grid, 64, 0, stream>>>(
        x, h0, c0, Wf, bf, Wi, bi, Wc, bc, Wo, bo, Ww, out);
  }
}